// Round 1
// baseline (511.073 us; speedup 1.0000x reference)
//
#include <hip/hip_runtime.h>

typedef _Float16 f16x8 __attribute__((ext_vector_type(8)));
typedef _Float16 f16x4 __attribute__((ext_vector_type(4)));
typedef float    f32x4 __attribute__((ext_vector_type(4)));

#define MFMA16(a, b, c) __builtin_amdgcn_mfma_f32_16x16x32_f16((a), (b), (c), 0, 0, 0)

static constexpr int SEQ   = 2048;
static constexpr int DIM   = 128;
static constexpr int QBLK  = 128;          // q rows per block (32 per wave)
static constexpr int KVBLK = 64;           // kv rows per tile
static constexpr int NKT   = SEQ / KVBLK;  // 32
static constexpr int BH    = 2 * 16;

// o = exp(QK^T - rowmax) @ V   (unnormalized, fp32 in/out)
__global__ __launch_bounds__(256, 2)
void fa_fwd_kernel(const float* __restrict__ Qg, const float* __restrict__ Kg,
                   const float* __restrict__ Vg, float* __restrict__ Og)
{
    // K tile hi/lo, row-major [k][d], byte ^ ((k&7)<<4) swizzle (G4 fix for 256B rows)
    __shared__ _Float16 Ksh[KVBLK * DIM];
    __shared__ _Float16 Ksl[KVBLK * DIM];
    // V transposed [d][k], row stride 72 (144B = 9*16B keeps b128 alignment, odd*4B spreads banks),
    // extra byte ^ (((d>>5)&3)<<4) to decorrelate the 4 c0 staging groups
    __shared__ _Float16 Vt[DIM * 72];
    // per-wave P [q(32)][k(64)], byte ^ ((q&7)<<4)
    __shared__ _Float16 Pb[4][QBLK / 4 * KVBLK];

    const int tid  = threadIdx.x;
    const int wv   = tid >> 6;
    const int lane = tid & 63;
    const int lg   = lane >> 4;   // 0..3
    const int lr   = lane & 15;   // 0..15

    const int bh = blockIdx.y;
    const size_t base = (size_t)bh * SEQ * DIM;
    const float* Qp = Qg + base;
    const float* Kp = Kg + base;
    const float* Vp = Vg + base;
    float*       Op = Og + base;

    const int qrow0 = blockIdx.x * QBLK + wv * 32;   // this wave's first q row

    // ---- Q fragments in registers, f16 hi/lo split.
    // A-frag (16x16x32): lane holds row=lr, k-elems d = ks*32 + lg*8 + j (contiguous 8)
    f16x8 qh[2][4], ql[2][4];
#pragma unroll
    for (int mi = 0; mi < 2; ++mi) {
        const float* qsrc = Qp + (size_t)(qrow0 + mi * 16 + lr) * DIM + lg * 8;
#pragma unroll
        for (int ks = 0; ks < 4; ++ks) {
            const float4 a = *(const float4*)(qsrc + ks * 32);
            const float4 b = *(const float4*)(qsrc + ks * 32 + 4);
            float xs[8] = {a.x, a.y, a.z, a.w, b.x, b.y, b.z, b.w};
            f16x8 h, l;
#pragma unroll
            for (int j = 0; j < 8; ++j) {
                _Float16 hh = (_Float16)xs[j];
                h[j] = hh;
                l[j] = (_Float16)(xs[j] - (float)hh);
            }
            qh[mi][ks] = h;
            ql[mi][ks] = l;
        }
    }

    // O accumulators: acc[mi][n] covers rows (mi*16 + lg*4 + r), cols (n*16 + lr)
    f32x4 acc[2][8];
#pragma unroll
    for (int mi = 0; mi < 2; ++mi)
#pragma unroll
        for (int n = 0; n < 8; ++n)
#pragma unroll
            for (int r = 0; r < 4; ++r) acc[mi][n][r] = 0.0f;

    float mrow[2][4];
#pragma unroll
    for (int mi = 0; mi < 2; ++mi)
#pragma unroll
        for (int r = 0; r < 4; ++r) mrow[mi][r] = -1e30f;

    // staging map: 4 threads per kv row, 8 float4 each
    const int sr  = tid >> 2;         // 0..63
    const int sc0 = (tid & 3) * 32;   // 0,32,64,96

    for (int kt = 0; kt < NKT; ++kt) {
        __syncthreads();   // protect previous tile's LDS reads
        {
            const float* ksrc = Kp + (size_t)(kt * KVBLK + sr) * DIM + sc0;
            const float* vsrc = Vp + (size_t)(kt * KVBLK + sr) * DIM + sc0;
#pragma unroll
            for (int i = 0; i < 8; ++i) {
                const float4 kk = *(const float4*)(ksrc + i * 4);
                float xs[4] = {kk.x, kk.y, kk.z, kk.w};
                f16x4 h, l;
#pragma unroll
                for (int j = 0; j < 4; ++j) {
                    _Float16 hh = (_Float16)xs[j];
                    h[j] = hh;
                    l[j] = (_Float16)(xs[j] - (float)hh);
                }
                const int c  = sc0 + i * 4;
                const int bo = (sr * DIM + c) * 2;
                const int sw = bo ^ ((sr & 7) << 4);
                *(f16x4*)((char*)Ksh + sw) = h;
                *(f16x4*)((char*)Ksl + sw) = l;

                const float4 vv = *(const float4*)(vsrc + i * 4);
                float vs[4] = {vv.x, vv.y, vv.z, vv.w};
#pragma unroll
                for (int jj = 0; jj < 4; ++jj) {
                    const int j = (jj + sr) & 3;   // stagger to spread banks
                    const int d = c + j;
                    const int vbo = (d * 72 + sr) * 2;
                    *(_Float16*)((char*)Vt + (vbo ^ (((d >> 5) & 3) << 4))) = (_Float16)vs[j];
                }
            }
        }
        __syncthreads();

        // ---- S = Q K^T (per wave: 32 q x 64 k), f16x3
        f32x4 s[2][4];
#pragma unroll
        for (int mi = 0; mi < 2; ++mi)
#pragma unroll
            for (int f = 0; f < 4; ++f)
#pragma unroll
                for (int r = 0; r < 4; ++r) s[mi][f][r] = 0.0f;

#pragma unroll
        for (int f = 0; f < 4; ++f) {
            const int krow = f * 16 + lr;   // B-frag: col k = krow, elems d = ks*32 + lg*8 + j
#pragma unroll
            for (int ks = 0; ks < 4; ++ks) {
                const int bo = (krow * DIM + ks * 32 + lg * 8) * 2;
                const int sw = bo ^ ((krow & 7) << 4);
                f16x8 bh_ = *(f16x8*)((char*)Ksh + sw);
                f16x8 bl_ = *(f16x8*)((char*)Ksl + sw);
                s[0][f] = MFMA16(qh[0][ks], bh_, s[0][f]);
                s[1][f] = MFMA16(qh[1][ks], bh_, s[1][f]);
                s[0][f] = MFMA16(ql[0][ks], bh_, s[0][f]);
                s[1][f] = MFMA16(ql[1][ks], bh_, s[1][f]);
                s[0][f] = MFMA16(qh[0][ks], bl_, s[0][f]);
                s[1][f] = MFMA16(qh[1][ks], bl_, s[1][f]);
            }
        }

        // ---- online row stats + P into LDS
#pragma unroll
        for (int mi = 0; mi < 2; ++mi) {
#pragma unroll
            for (int r = 0; r < 4; ++r) {
                float t = fmaxf(fmaxf(s[mi][0][r], s[mi][1][r]),
                                fmaxf(s[mi][2][r], s[mi][3][r]));
                t = fmaxf(t, __shfl_xor(t, 1));
                t = fmaxf(t, __shfl_xor(t, 2));
                t = fmaxf(t, __shfl_xor(t, 4));
                t = fmaxf(t, __shfl_xor(t, 8));
                const float mo = mrow[mi][r];
                const float mn = fmaxf(mo, t);
                const float sc = __expf(mo - mn);
                mrow[mi][r] = mn;
#pragma unroll
                for (int n = 0; n < 8; ++n) acc[mi][n][r] *= sc;
                const int q = mi * 16 + lg * 4 + r;
#pragma unroll
                for (int f = 0; f < 4; ++f) {
                    const float p = __expf(s[mi][f][r] - mn);
                    const int bo = (q * KVBLK + f * 16 + lr) * 2;
                    *(_Float16*)((char*)&Pb[wv][0] + (bo ^ ((q & 7) << 4))) = (_Float16)p;
                }
            }
        }

        // ---- O += P V
#pragma unroll
        for (int ks = 0; ks < 2; ++ks) {
            f16x8 pa[2];
#pragma unroll
            for (int mi = 0; mi < 2; ++mi) {
                const int q  = mi * 16 + lr;
                const int bo = (q * KVBLK + ks * 32 + lg * 8) * 2;
                pa[mi] = *(f16x8*)((char*)&Pb[wv][0] + (bo ^ ((q & 7) << 4)));
            }
#pragma unroll
            for (int n = 0; n < 8; ++n) {
                const int d  = n * 16 + lr;
                const int bo = (d * 72 + ks * 32 + lg * 8) * 2;
                f16x8 vb = *(f16x8*)((char*)Vt + (bo ^ (((d >> 5) & 3) << 4)));
                acc[0][n] = MFMA16(pa[0], vb, acc[0][n]);
                acc[1][n] = MFMA16(pa[1], vb, acc[1][n]);
            }
        }
    }

    // ---- write O (fp32, unnormalized)
#pragma unroll
    for (int mi = 0; mi < 2; ++mi)
#pragma unroll
        for (int n = 0; n < 8; ++n)
#pragma unroll
            for (int r = 0; r < 4; ++r)
                Op[(size_t)(qrow0 + mi * 16 + lg * 4 + r) * DIM + n * 16 + lr] = acc[mi][n][r];
}

extern "C" void kernel_launch(void* const* d_in, const int* in_sizes, int n_in,
                              void* d_out, int out_size, void* d_ws, size_t ws_size,
                              hipStream_t stream) {
    const float* q = (const float*)d_in[0];
    const float* k = (const float*)d_in[1];
    const float* v = (const float*)d_in[2];
    float* o = (float*)d_out;
    dim3 grid(SEQ / QBLK, BH);
    fa_fwd_kernel<<<grid, dim3(256), 0, stream>>>(q, k, v, o);
}

// Round 2
// 340.145 us; speedup vs baseline: 1.5025x; 1.5025x over previous
//
#include <hip/hip_runtime.h>

typedef _Float16 f16x8 __attribute__((ext_vector_type(8)));
typedef _Float16 f16x2 __attribute__((ext_vector_type(2)));
typedef float    f32x4 __attribute__((ext_vector_type(4)));

#define MFMA16(a, b, c) __builtin_amdgcn_mfma_f32_16x16x32_f16((a), (b), (c), 0, 0, 0)

static constexpr int SEQ   = 2048;
static constexpr int DIM   = 128;
static constexpr int QBLK  = 64;           // q rows per block (16 per wave)
static constexpr int KVBLK = 64;           // kv rows per tile
static constexpr int NKT   = SEQ / KVBLK;  // 32
static constexpr int BH    = 2 * 16;

// o = exp(QK^T - rowmax) @ V  (unnormalized, fp32 in/out)
// Swapped-operand structure: S^T = mfma(K,Q), in-register softmax (q = lr per lane),
// P redistributed via shfl (no LDS bounce), O^T = mfma(V^T, P^T).
__global__ __launch_bounds__(256, 3)
void fa_fwd_kernel(const float* __restrict__ Qg, const float* __restrict__ Kg,
                   const float* __restrict__ Vg, float* __restrict__ Og)
{
    // K hi/lo f16, row-major [k][d], byte ^ ((k&7)<<4)
    __shared__ _Float16 Ksh[KVBLK * DIM];
    __shared__ _Float16 Ksl[KVBLK * DIM];
    // V transposed [d][k], byte ^ (((d&7)^((d>>2)&7))<<4)  (conflict-free for both
    // the b128 transpose-writes and the PV A-frag b128 reads)
    __shared__ _Float16 Vt[DIM * KVBLK];

    const int tid  = threadIdx.x;
    const int wv   = tid >> 6;
    const int lane = tid & 63;
    const int lr   = lane & 15;   // q column owned by this lane
    const int lg   = lane >> 4;   // 0..3

    // XCD-aware swizzle: all 32 q-tiles of one bh dispatch at i===bh (mod 8)
    // -> same XCD -> K/V tile L2-resident. Bijection over 1024 blocks.
    const int bi = blockIdx.x;
    const int bh = (bi & 7) + 8 * ((bi >> 3) >> 5);
    const int qt = (bi >> 3) & 31;

    const size_t base = (size_t)bh * SEQ * DIM;
    const float* Qp = Qg + base;
    const float* Kp = Kg + base;
    const float* Vp = Vg + base;
    float*       Op = Og + base;

    const int q0 = qt * QBLK + wv * 16;   // this wave's first q row

    // ---- Q fragments (B-operand: col q = lr, elems d = dc*32 + lg*8 + e), f16 hi/lo
    f16x8 qh[4], ql[4];
    {
        const float* qs = Qp + (size_t)(q0 + lr) * DIM + lg * 8;
#pragma unroll
        for (int dc = 0; dc < 4; ++dc) {
            const float4 a = *(const float4*)(qs + dc * 32);
            const float4 b = *(const float4*)(qs + dc * 32 + 4);
            float xs[8] = {a.x, a.y, a.z, a.w, b.x, b.y, b.z, b.w};
            f16x8 h, l;
#pragma unroll
            for (int e = 0; e < 8; ++e) {
                _Float16 hh = (_Float16)xs[e];
                h[e] = hh;
                l[e] = (_Float16)(xs[e] - (float)hh);
            }
            qh[dc] = h; ql[dc] = l;
        }
    }

    // O^T accumulators: acc[dm] rows d = dm*16 + lg*4 + r, col q = lr
    f32x4 acc[8];
#pragma unroll
    for (int d = 0; d < 8; ++d)
#pragma unroll
        for (int r = 0; r < 4; ++r) acc[d][r] = 0.0f;

    float mrow = -3.0e38f;   // running row max for q = lr

    // staging maps
    const int ksr = tid >> 2, kc0 = (tid & 3) * 32;            // K: row, 32 cols
    const int vd0 = (tid & 31) * 4, vk0 = (tid >> 5) * 8;      // V: 4 d cols, 8 k rows
    const int swzKw = (ksr & 7) << 4;
    const int swzKr = (lr & 7) << 4;

    for (int kt = 0; kt < NKT; ++kt) {
        // ---- issue global loads before the barrier (overlap prior compute tail)
        const float* ks_ = Kp + (size_t)(kt * KVBLK + ksr) * DIM + kc0;
        const float* vs_ = Vp + (size_t)(kt * KVBLK + vk0) * DIM + vd0;
        float4 kreg[8], vreg[8];
#pragma unroll
        for (int t = 0; t < 8; ++t) kreg[t] = *(const float4*)(ks_ + t * 4);
#pragma unroll
        for (int t = 0; t < 8; ++t) vreg[t] = *(const float4*)(vs_ + (size_t)t * DIM);

        __syncthreads();   // previous tile's LDS reads complete

        // ---- K -> LDS hi/lo, b128 writes
#pragma unroll
        for (int g = 0; g < 4; ++g) {
            float xs[8] = {kreg[2*g].x, kreg[2*g].y, kreg[2*g].z, kreg[2*g].w,
                           kreg[2*g+1].x, kreg[2*g+1].y, kreg[2*g+1].z, kreg[2*g+1].w};
            f16x8 h, l;
#pragma unroll
            for (int e = 0; e < 8; ++e) {
                _Float16 hh = (_Float16)xs[e];
                h[e] = hh;
                l[e] = (_Float16)(xs[e] - (float)hh);
            }
            const int off = ((ksr * DIM + kc0 + g * 8) * 2) ^ swzKw;
            *(f16x8*)((char*)Ksh + off) = h;
            *(f16x8*)((char*)Ksl + off) = l;
        }
        // ---- V -> LDS transposed via register 8x4 transpose, b128 writes
#pragma unroll
        for (int dj = 0; dj < 4; ++dj) {
            f16x8 tv;
#pragma unroll
            for (int t = 0; t < 8; ++t) tv[t] = (_Float16)(((const float*)&vreg[t])[dj]);
            const int d   = vd0 + dj;
            const int off = ((d * KVBLK + vk0) * 2) ^ ((((d & 7) ^ ((d >> 2) & 7)) << 4));
            *(f16x8*)((char*)Vt + off) = tv;
        }
        __syncthreads();

        // ---- S^T = K Q^T (f16x3): st[kf] rows k = kf*16 + lg*4 + r, col q = lr
        f32x4 st[4];
#pragma unroll
        for (int kf = 0; kf < 4; ++kf)
#pragma unroll
            for (int r = 0; r < 4; ++r) st[kf][r] = 0.0f;
#pragma unroll
        for (int kf = 0; kf < 4; ++kf) {
            const int rb = (kf * 16 + lr) * (DIM * 2) + lg * 16;
#pragma unroll
            for (int dc = 0; dc < 4; ++dc) {
                const int off = (rb + dc * 64) ^ swzKr;
                f16x8 kh = *(const f16x8*)((const char*)Ksh + off);
                f16x8 kl = *(const f16x8*)((const char*)Ksl + off);
                st[kf] = MFMA16(kh, qh[dc], st[kf]);
                st[kf] = MFMA16(kl, qh[dc], st[kf]);
                st[kf] = MFMA16(kh, ql[dc], st[kf]);
            }
        }

        // ---- online softmax fully in-register (row q = lr spread over 4 lg-lanes)
        float tmax = st[0][0];
#pragma unroll
        for (int kf = 0; kf < 4; ++kf)
#pragma unroll
            for (int r = 0; r < 4; ++r) tmax = fmaxf(tmax, st[kf][r]);
        tmax = fmaxf(tmax, __shfl_xor(tmax, 16));
        tmax = fmaxf(tmax, __shfl_xor(tmax, 32));
        const float mn  = fmaxf(mrow, tmax);
        const float scl = __expf(mrow - mn);
        mrow = mn;
#pragma unroll
        for (int d = 0; d < 8; ++d)
#pragma unroll
            for (int r = 0; r < 4; ++r) acc[d][r] *= scl;

        // P^T packed f16: p2i[kf] = {P^T[kf*16+lg*4+r][lr]}, r=0..3
        int p2i[4][2];
#pragma unroll
        for (int kf = 0; kf < 4; ++kf) {
            f16x2 e0 = {(_Float16)__expf(st[kf][0] - mn), (_Float16)__expf(st[kf][1] - mn)};
            f16x2 e1 = {(_Float16)__expf(st[kf][2] - mn), (_Float16)__expf(st[kf][3] - mn)};
            p2i[kf][0] = __builtin_bit_cast(int, e0);
            p2i[kf][1] = __builtin_bit_cast(int, e1);
        }

        // ---- PV: O^T += V^T P^T. P^T B-frag needs k = ks*32 + lg*8 + j for col lr:
        // source lane = lr + 16*((2lg+t)&3), source reg f = 2ks + (lg>>1)  (verified alg.)
        const int srcA = lr + 16 * ((2 * lg) & 3);
        const int srcB = lr + 16 * ((2 * lg + 1) & 3);
        const bool hiF = (lg >> 1) != 0;
#pragma unroll
        for (int ks = 0; ks < 2; ++ks) {
            const int f0 = 2 * ks, f1 = 2 * ks + 1;
            int a00 = __shfl(p2i[f0][0], srcA), a01 = __shfl(p2i[f0][1], srcA);
            int a10 = __shfl(p2i[f1][0], srcA), a11 = __shfl(p2i[f1][1], srcA);
            int b00 = __shfl(p2i[f0][0], srcB), b01 = __shfl(p2i[f0][1], srcB);
            int b10 = __shfl(p2i[f1][0], srcB), b11 = __shfl(p2i[f1][1], srcB);
            union { int i[4]; f16x8 v; } u;
            u.i[0] = hiF ? a10 : a00;
            u.i[1] = hiF ? a11 : a01;
            u.i[2] = hiF ? b10 : b00;
            u.i[3] = hiF ? b11 : b01;
            const f16x8 vb = u.v;
#pragma unroll
            for (int dm = 0; dm < 8; ++dm) {
                const int d   = dm * 16 + lr;
                const int off = ((d * KVBLK + ks * 32 + lg * 8) * 2)
                                ^ ((((d & 7) ^ ((d >> 2) & 7)) << 4));
                f16x8 va = *(const f16x8*)((const char*)Vt + off);
                acc[dm] = MFMA16(va, vb, acc[dm]);
            }
        }
    }

    // ---- store O (acc rows are contiguous in d -> coalesced f32x4, no transpose)
    float* ob = Op + (size_t)(q0 + lr) * DIM + lg * 4;
#pragma unroll
    for (int dm = 0; dm < 8; ++dm) *(f32x4*)(ob + dm * 16) = acc[dm];
}

extern "C" void kernel_launch(void* const* d_in, const int* in_sizes, int n_in,
                              void* d_out, int out_size, void* d_ws, size_t ws_size,
                              hipStream_t stream) {
    const float* q = (const float*)d_in[0];
    const float* k = (const float*)d_in[1];
    const float* v = (const float*)d_in[2];
    float* o = (float*)d_out;
    dim3 grid((SEQ / QBLK) * BH);   // 1024 blocks, XCD-swizzled inside the kernel
    fa_fwd_kernel<<<grid, dim3(256), 0, stream>>>(q, k, v, o);
}